// Round 1
// baseline (88321.417 us; speedup 1.0000x reference)
//
#include <hip/hip_runtime.h>
#include <hip/hip_bf16.h>

// LSTM (2-layer, T=1024) + STE binarize + FC, MI355X.
// Strategy: persistent 256-block kernel, 1 grid barrier per timestep-phase,
// split-f16 (hi+lo) 3-product MFMA GEMMs for fp32-grade precision, fp32 cell math.

typedef _Float16 f16;
typedef __attribute__((ext_vector_type(8))) _Float16 f16x8;
typedef __attribute__((ext_vector_type(2))) _Float16 f16x2;
typedef __attribute__((ext_vector_type(4))) float f32x4;

#define MFMA16(a, b, c) __builtin_amdgcn_mfma_f32_16x16x32_f16((a), (b), (c), 0, 0, 0)

#define NB 512      // batch
#define NT 1024     // timesteps
#define NF 128      // input features
#define NH 512      // hidden
#define NGC 2048    // 4*NH gate columns
#define K0 640      // NH + NF   (L0: [h0_prev | x_t])
#define K1 1024     // 2*NH      (L1: [h0_t | h1_prev])
#define HBUF 262144 // NB*NH elements per h half-buffer
#define NBLK 256
#define NTHR 512

__device__ __forceinline__ float sigf(float v) { return 1.0f / (1.0f + expf(-v)); }

__device__ __forceinline__ void split8(const float* __restrict__ p, f16x8& hi, f16x8& lo) {
    f32x4 u0 = *(const f32x4*)p;
    f32x4 u1 = *(const f32x4*)(p + 4);
#pragma unroll
    for (int e = 0; e < 4; ++e) {
        float v = u0[e];
        f16 h = (f16)v;
        hi[e] = h;
        lo[e] = (f16)(v - (float)h);
    }
#pragma unroll
    for (int e = 0; e < 4; ++e) {
        float v = u1[e];
        f16 h = (f16)v;
        hi[4 + e] = h;
        lo[4 + e] = (f16)(v - (float)h);
    }
}

// ---------------- prep: split weights into packed hi/lo f16, sum biases ----------------
__global__ __launch_bounds__(256) void prep_kernel(
    const float* __restrict__ Wih0, const float* __restrict__ Whh0,
    const float* __restrict__ bih0, const float* __restrict__ bhh0,
    const float* __restrict__ Wih1, const float* __restrict__ Whh1,
    const float* __restrict__ bih1, const float* __restrict__ bhh1,
    f16* __restrict__ W0h, f16* __restrict__ W0l,
    f16* __restrict__ W1h, f16* __restrict__ W1l,
    float* __restrict__ bias0, float* __restrict__ bias1)
{
    const int stride = gridDim.x * blockDim.x;
    const int idx = blockIdx.x * blockDim.x + threadIdx.x;
    const int total0 = NGC * K0;
    for (int i = idx; i < total0; i += stride) {
        int gc = i / K0, k = i - gc * K0;
        float w = (k < NH) ? Whh0[gc * NH + k] : Wih0[gc * NF + (k - NH)];
        f16 h = (f16)w;
        W0h[i] = h;
        W0l[i] = (f16)(w - (float)h);
    }
    const int total1 = NGC * K1;
    for (int i = idx; i < total1; i += stride) {
        int gc = i / K1, k = i - gc * K1;
        float w = (k < NH) ? Wih1[gc * NH + k] : Whh1[gc * NH + (k - NH)];
        f16 h = (f16)w;
        W1h[i] = h;
        W1l[i] = (f16)(w - (float)h);
    }
    for (int i = idx; i < NGC; i += stride) {
        bias0[i] = bih0[i] + bhh0[i];
        bias1[i] = bih1[i] + bhh1[i];
    }
}

// ---------------- main persistent LSTM kernel ----------------
__global__ __launch_bounds__(NTHR) void lstm_kernel(
    const float* __restrict__ x,
    const f16* __restrict__ W0h, const f16* __restrict__ W0l,
    const f16* __restrict__ W1h, const f16* __restrict__ W1l,
    const float* __restrict__ bias0, const float* __restrict__ bias1,
    f16* __restrict__ hb, unsigned* __restrict__ ctr,
    float* __restrict__ h1f)
{
    const int tid = threadIdx.x;
    const int bid = blockIdx.x;
    const int lane = tid & 63;
    const int wave = tid >> 6;       // 0..7
    const int gate = wave & 3;       // i,f,g,o
    const int rowHalf = wave >> 2;   // 0..1 (32 rows each)
    const int kg = lane >> 4;        // k-group 0..3
    const int lm = lane & 15;

    // XCD-aware tile map: same col-tiles stay on one XCD -> weights L2-resident
    const int xcd = bid & 7;
    const int sub = bid >> 3;               // 0..31
    const int colTile = xcd * 4 + (sub & 3); // 0..31 (16 h-cols each)
    const int rowTile = sub >> 2;            // 0..7  (64 rows each)
    const int row0 = rowTile * 64;

    const int gc = gate * NH + colTile * 16 + lm; // gate column this lane owns (B frag col)
    const int rA0 = row0 + rowHalf * 32 + lm;     // A frag rows
    const int rA1 = rA0 + 16;

    const float bi0 = bias0[gc];
    const float bi1 = bias1[gc];

    // fixed per-lane weight pointers (include kg*8 lane offset)
    const f16* pw0h = W0h + (size_t)gc * K0 + kg * 8;
    const f16* pw0l = W0l + (size_t)gc * K0 + kg * 8;
    const f16* pw1h = W1h + (size_t)gc * K1 + kg * 8;
    const f16* pw1l = W1l + (size_t)gc * K1 + kg * 8;

    __shared__ float ldsG[2][4][64][17]; // [layer][gate][row][col], padded

    float c0[2] = {0.f, 0.f}, c1[2] = {0.f, 0.f};
    const int er = tid >> 3;        // epilogue row 0..63
    const int ej = (tid & 7) * 2;   // epilogue col pair 0,2,..,14
    const int ecol = colTile * 16 + ej;

    for (int p = 0; p <= NT; ++p) {
        const int pb = (p - 1) & 1; // h0(p-1) read buf; h1(p-1) write buf
        const int cb = p & 1;       // h0(p) write buf;  h1(p-2) read buf

        const f16* h0h = hb + (size_t)(0 + pb) * HBUF;
        const f16* h0l = hb + (size_t)(2 + pb) * HBUF;
        const f16* h1h = hb + (size_t)(4 + cb) * HBUF;
        const f16* h1l = hb + (size_t)(6 + cb) * HBUF;

        f32x4 a00 = {bi0, bi0, bi0, bi0}, a01 = a00; // L0 accum, frags 0/1
        f32x4 a10 = {bi1, bi1, bi1, bi1}, a11 = a10; // L1 accum

        // ---- shared A slabs: h0(p-1), K 0..511 feeds BOTH layers ----
        {
            const f16* pa0h = h0h + (size_t)rA0 * NH + kg * 8;
            const f16* pa0l = h0l + (size_t)rA0 * NH + kg * 8;
            const f16* pa1h = h0h + (size_t)rA1 * NH + kg * 8;
            const f16* pa1l = h0l + (size_t)rA1 * NH + kg * 8;
#pragma unroll 2
            for (int s = 0; s < 16; ++s) {
                const int kb = s * 32;
                f16x8 A0h = *(const f16x8*)(pa0h + kb);
                f16x8 A0l = *(const f16x8*)(pa0l + kb);
                f16x8 A1h = *(const f16x8*)(pa1h + kb);
                f16x8 A1l = *(const f16x8*)(pa1l + kb);
                f16x8 B0h = *(const f16x8*)(pw0h + kb);
                f16x8 B0l = *(const f16x8*)(pw0l + kb);
                f16x8 B1h = *(const f16x8*)(pw1h + kb);
                f16x8 B1l = *(const f16x8*)(pw1l + kb);
                a00 = MFMA16(A0h, B0h, a00); a00 = MFMA16(A0h, B0l, a00); a00 = MFMA16(A0l, B0h, a00);
                a01 = MFMA16(A1h, B0h, a01); a01 = MFMA16(A1h, B0l, a01); a01 = MFMA16(A1l, B0h, a01);
                a10 = MFMA16(A0h, B1h, a10); a10 = MFMA16(A0h, B1l, a10); a10 = MFMA16(A0l, B1h, a10);
                a11 = MFMA16(A1h, B1h, a11); a11 = MFMA16(A1h, B1l, a11); a11 = MFMA16(A1l, B1h, a11);
            }
        }

        // ---- x slabs (L0 only): weight K 512..639 ----
        if (p < NT) {
            const float* px0 = x + ((size_t)rA0 * NT + p) * NF + kg * 8;
            const float* px1 = x + ((size_t)rA1 * NT + p) * NF + kg * 8;
#pragma unroll
            for (int s = 0; s < 4; ++s) {
                const int fb = s * 32;
                f16x8 A0h, A0l, A1h, A1l;
                split8(px0 + fb, A0h, A0l);
                split8(px1 + fb, A1h, A1l);
                const int kb = NH + fb;
                f16x8 B0h = *(const f16x8*)(pw0h + kb);
                f16x8 B0l = *(const f16x8*)(pw0l + kb);
                a00 = MFMA16(A0h, B0h, a00); a00 = MFMA16(A0h, B0l, a00); a00 = MFMA16(A0l, B0h, a00);
                a01 = MFMA16(A1h, B0h, a01); a01 = MFMA16(A1h, B0l, a01); a01 = MFMA16(A1l, B0h, a01);
            }
        }

        // ---- h1(p-2) slabs (L1 only): weight K 512..1023 ----
        {
            const f16* qa0h = h1h + (size_t)rA0 * NH + kg * 8;
            const f16* qa0l = h1l + (size_t)rA0 * NH + kg * 8;
            const f16* qa1h = h1h + (size_t)rA1 * NH + kg * 8;
            const f16* qa1l = h1l + (size_t)rA1 * NH + kg * 8;
#pragma unroll 2
            for (int s = 0; s < 16; ++s) {
                const int kb = s * 32;
                f16x8 A0h = *(const f16x8*)(qa0h + kb);
                f16x8 A0l = *(const f16x8*)(qa0l + kb);
                f16x8 A1h = *(const f16x8*)(qa1h + kb);
                f16x8 A1l = *(const f16x8*)(qa1l + kb);
                const int kw = NH + kb;
                f16x8 B1h = *(const f16x8*)(pw1h + kw);
                f16x8 B1l = *(const f16x8*)(pw1l + kw);
                a10 = MFMA16(A0h, B1h, a10); a10 = MFMA16(A0h, B1l, a10); a10 = MFMA16(A0l, B1h, a10);
                a11 = MFMA16(A1h, B1h, a11); a11 = MFMA16(A1h, B1l, a11); a11 = MFMA16(A1l, B1h, a11);
            }
        }

        // ---- dump gates to LDS (C/D layout: col=lane&15, row=(lane>>4)*4+reg) ----
#pragma unroll
        for (int rg = 0; rg < 4; ++rg) {
            const int r0w = rowHalf * 32 + kg * 4 + rg;
            ldsG[0][gate][r0w][lm] = a00[rg];
            ldsG[0][gate][r0w + 16][lm] = a01[rg];
            ldsG[1][gate][r0w][lm] = a10[rg];
            ldsG[1][gate][r0w + 16][lm] = a11[rg];
        }
        __syncthreads();

        // ---- fused cell updates (fp32) ----
        const size_t off = (size_t)(row0 + er) * NH + ecol;
        if (p < NT) {
            f16 hh[2], hl[2];
#pragma unroll
            for (int e = 0; e < 2; ++e) {
                const int jj = ej + e;
                const float gi = ldsG[0][0][er][jj];
                const float gf = ldsG[0][1][er][jj];
                const float gg = ldsG[0][2][er][jj];
                const float go = ldsG[0][3][er][jj];
                const float cn = sigf(gf) * c0[e] + sigf(gi) * tanhf(gg);
                c0[e] = cn;
                const float h = sigf(go) * tanhf(cn);
                hh[e] = (f16)h;
                hl[e] = (f16)(h - (float)hh[e]);
            }
            f16x2 vh = {hh[0], hh[1]}, vl = {hl[0], hl[1]};
            *(f16x2*)(hb + (size_t)(0 + cb) * HBUF + off) = vh;
            *(f16x2*)(hb + (size_t)(2 + cb) * HBUF + off) = vl;
        }
        if (p >= 1) {
            f16 hh[2], hl[2];
            float hv[2];
#pragma unroll
            for (int e = 0; e < 2; ++e) {
                const int jj = ej + e;
                const float gi = ldsG[1][0][er][jj];
                const float gf = ldsG[1][1][er][jj];
                const float gg = ldsG[1][2][er][jj];
                const float go = ldsG[1][3][er][jj];
                const float cn = sigf(gf) * c1[e] + sigf(gi) * tanhf(gg);
                c1[e] = cn;
                const float h = sigf(go) * tanhf(cn);
                hv[e] = h;
                hh[e] = (f16)h;
                hl[e] = (f16)(h - (float)hh[e]);
            }
            f16x2 vh = {hh[0], hh[1]}, vl = {hl[0], hl[1]};
            *(f16x2*)(hb + (size_t)(4 + pb) * HBUF + off) = vh;
            *(f16x2*)(hb + (size_t)(6 + pb) * HBUF + off) = vl;
            if (p == NT) {
                h1f[off] = hv[0];
                h1f[off + 1] = hv[1];
            }
        }

        // ---- grid barrier (skip after last phase) ----
        if (p < NT) {
            __syncthreads();
            if (tid == 0) {
                __threadfence(); // agent-scope release of this block's h writes
                __hip_atomic_fetch_add(ctr, 1u, __ATOMIC_RELEASE, __HIP_MEMORY_SCOPE_AGENT);
                const unsigned tgt = (unsigned)(p + 1) * NBLK;
                while (__hip_atomic_load(ctr, __ATOMIC_ACQUIRE, __HIP_MEMORY_SCOPE_AGENT) < tgt) {
                    __builtin_amdgcn_s_sleep(1);
                }
                __threadfence(); // acquire side: invalidate caches for fresh h reads
            }
            __syncthreads();
        }
    }
}

// ---------------- binarize + FC ----------------
__global__ __launch_bounds__(256) void fc_kernel(
    const float* __restrict__ h1f, const float* __restrict__ Wfc,
    const float* __restrict__ bfc, float* __restrict__ out)
{
    const int t = blockIdx.x * blockDim.x + threadIdx.x; // 0..16383
    const int b = t >> 5;
    const int o = t & 31;
    const float* hr = h1f + (size_t)b * NH;
    const float* wr = Wfc + (size_t)o * NH;
    float s = 0.f;
    for (int j = 0; j < NH; ++j) {
        s += (hr[j] > 0.0f) ? wr[j] : 0.0f;
    }
    out[t] = s + bfc[o];
}

extern "C" void kernel_launch(void* const* d_in, const int* in_sizes, int n_in,
                              void* d_out, int out_size, void* d_ws, size_t ws_size,
                              hipStream_t stream) {
    const float* x    = (const float*)d_in[0];
    const float* Wih0 = (const float*)d_in[1];
    const float* Whh0 = (const float*)d_in[2];
    const float* bih0 = (const float*)d_in[3];
    const float* bhh0 = (const float*)d_in[4];
    const float* Wih1 = (const float*)d_in[5];
    const float* Whh1 = (const float*)d_in[6];
    const float* bih1 = (const float*)d_in[7];
    const float* bhh1 = (const float*)d_in[8];
    const float* Wfc  = (const float*)d_in[9];
    const float* bfc  = (const float*)d_in[10];
    float* out = (float*)d_out;
    (void)in_sizes; (void)n_in; (void)out_size; (void)ws_size;

    // workspace layout (~18.9 MB total)
    char* w = (char*)d_ws;
    unsigned* ctr = (unsigned*)w;                               // 256 B
    f16* hb = (f16*)(w + 256);                                  // 8 * 512 KB h split buffers
    char* after_hb = w + 256 + 8 * (size_t)HBUF * sizeof(f16);
    float* h1f = (float*)after_hb;                              // 1 MB
    float* bias0 = (float*)(after_hb + (size_t)NB * NH * 4);
    float* bias1 = bias0 + NGC;
    f16* W0h = (f16*)(bias1 + NGC);
    f16* W0l = W0h + (size_t)NGC * K0;
    f16* W1h = W0l + (size_t)NGC * K0;
    f16* W1l = W1h + (size_t)NGC * K1;

    // zero: counter + h state buffers (h(-1)=0); replayed each graph launch
    hipMemsetAsync(d_ws, 0, 256 + 8 * (size_t)HBUF * sizeof(f16), stream);

    prep_kernel<<<2048, 256, 0, stream>>>(Wih0, Whh0, bih0, bhh0, Wih1, Whh1, bih1, bhh1,
                                          W0h, W0l, W1h, W1l, bias0, bias1);

    lstm_kernel<<<NBLK, NTHR, 0, stream>>>(x, W0h, W0l, W1h, W1l, bias0, bias1, hb, ctr, h1f);

    fc_kernel<<<64, 256, 0, stream>>>(h1f, Wfc, bfc, out);
}

// Round 2
// 66693.719 us; speedup vs baseline: 1.3243x; 1.3243x over previous
//
#include <hip/hip_runtime.h>
#include <hip/hip_bf16.h>

// LSTM (2-layer, T=1024) + STE binarize + FC, MI355X.
// Round 2: fence-free grid barrier. h-state moves via relaxed agent-scope
// atomics (sc0|sc1 coherent, L3-served) in a fragment-native layout, so the
// per-XCD L2 is never invalidated and weights/x stay L2-resident all 1024
// phases. 2-stage software pipeline on the GEMM slab loops.

typedef _Float16 f16;
typedef unsigned long long u64;
typedef __attribute__((ext_vector_type(8))) _Float16 f16x8;
typedef __attribute__((ext_vector_type(2))) _Float16 f16x2;
typedef __attribute__((ext_vector_type(4))) float f32x4;

#define MFMA16(a, b, c) __builtin_amdgcn_mfma_f32_16x16x32_f16((a), (b), (c), 0, 0, 0)

#define NB 512      // batch
#define NT 1024     // timesteps
#define NF 128      // input features
#define NH 512      // hidden
#define NGC 2048    // 4*NH gate columns
#define K0 640      // NH + NF   (L0: [h0_prev | x_t])
#define K1 1024     // 2*NH      (L1: [h0_t | h1_prev])
#define HBUF 262144 // NB*NH elements per h half-buffer
#define NBLK 256
#define NTHR 512

__device__ __forceinline__ float sigf(float v) { return 1.0f / (1.0f + expf(-v)); }

union FragU { u64 u[2]; f16x8 v; };

// coherent (agent-scope, L2-bypass) 16B load from frag-layout h buffer
__device__ __forceinline__ f16x8 cload(const f16* p) {
    FragU f;
    const u64* q = (const u64*)p;
    f.u[0] = __hip_atomic_load(q, __ATOMIC_RELAXED, __HIP_MEMORY_SCOPE_AGENT);
    f.u[1] = __hip_atomic_load(q + 1, __ATOMIC_RELAXED, __HIP_MEMORY_SCOPE_AGENT);
    return f.v;
}

// coherent 4B (f16x2) store
__device__ __forceinline__ void cstore2(f16* p, f16 a, f16 b) {
    union { f16 h[2]; unsigned u; } x;
    x.h[0] = a; x.h[1] = b;
    __hip_atomic_store((unsigned*)p, x.u, __ATOMIC_RELAXED, __HIP_MEMORY_SCOPE_AGENT);
}

// fragment-native element index for h buffers:
// [rowblk r>>4][kblk c>>5][lane = ((c>>3)&3)*16 + (r&15)][elem c&7]
__device__ __forceinline__ size_t hidx(int r, int c) {
    return ((size_t)(((r >> 4) * 16 + (c >> 5)) * 64 + ((c >> 3) & 3) * 16 + (r & 15))) * 8 + (c & 7);
}

__device__ __forceinline__ void split8(const float* __restrict__ p, f16x8& hi, f16x8& lo) {
    f32x4 u0 = *(const f32x4*)p;
    f32x4 u1 = *(const f32x4*)(p + 4);
#pragma unroll
    for (int e = 0; e < 4; ++e) {
        float v = u0[e];
        f16 h = (f16)v;
        hi[e] = h;
        lo[e] = (f16)(v - (float)h);
    }
#pragma unroll
    for (int e = 0; e < 4; ++e) {
        float v = u1[e];
        f16 h = (f16)v;
        hi[4 + e] = h;
        lo[4 + e] = (f16)(v - (float)h);
    }
}

// ---------------- prep: split weights into packed hi/lo f16, sum biases ----------------
__global__ __launch_bounds__(256) void prep_kernel(
    const float* __restrict__ Wih0, const float* __restrict__ Whh0,
    const float* __restrict__ bih0, const float* __restrict__ bhh0,
    const float* __restrict__ Wih1, const float* __restrict__ Whh1,
    const float* __restrict__ bih1, const float* __restrict__ bhh1,
    f16* __restrict__ W0h, f16* __restrict__ W0l,
    f16* __restrict__ W1h, f16* __restrict__ W1l,
    float* __restrict__ bias0, float* __restrict__ bias1)
{
    const int stride = gridDim.x * blockDim.x;
    const int idx = blockIdx.x * blockDim.x + threadIdx.x;
    const int total0 = NGC * K0;
    for (int i = idx; i < total0; i += stride) {
        int gc = i / K0, k = i - gc * K0;
        float w = (k < NH) ? Whh0[gc * NH + k] : Wih0[gc * NF + (k - NH)];
        f16 h = (f16)w;
        W0h[i] = h;
        W0l[i] = (f16)(w - (float)h);
    }
    const int total1 = NGC * K1;
    for (int i = idx; i < total1; i += stride) {
        int gc = i / K1, k = i - gc * K1;
        float w = (k < NH) ? Wih1[gc * NH + k] : Whh1[gc * NH + (k - NH)];
        f16 h = (f16)w;
        W1h[i] = h;
        W1l[i] = (f16)(w - (float)h);
    }
    for (int i = idx; i < NGC; i += stride) {
        bias0[i] = bih0[i] + bhh0[i];
        bias1[i] = bih1[i] + bhh1[i];
    }
}

// ---------------- main persistent LSTM kernel ----------------
__global__ __launch_bounds__(NTHR) void lstm_kernel(
    const float* __restrict__ x,
    const f16* __restrict__ W0h, const f16* __restrict__ W0l,
    const f16* __restrict__ W1h, const f16* __restrict__ W1l,
    const float* __restrict__ bias0, const float* __restrict__ bias1,
    f16* hb, unsigned* ctr,
    float* __restrict__ h1f)
{
    const int tid = threadIdx.x;
    const int bid = blockIdx.x;
    const int lane = tid & 63;
    const int wave = tid >> 6;       // 0..7
    const int gate = wave & 3;       // i,f,g,o
    const int rowHalf = wave >> 2;   // 0..1 (32 rows each)
    const int kg = lane >> 4;        // k-group 0..3
    const int lm = lane & 15;

    // XCD-aware tile map: same col-tiles stay on one XCD -> weights L2-resident
    const int xcd = bid & 7;
    const int sub = bid >> 3;                // 0..31
    const int colTile = xcd * 4 + (sub & 3); // 0..31 (16 h-cols each)
    const int rowTile = sub >> 2;            // 0..7  (64 rows each)
    const int row0 = rowTile * 64;

    const int gc = gate * NH + colTile * 16 + lm; // gate column this lane owns (B frag col)
    const int rA0 = row0 + rowHalf * 32 + lm;     // A frag rows (x loads only)
    const int rA1 = rA0 + 16;

    const float bi0 = bias0[gc];
    const float bi1 = bias1[gc];

    // per-lane weight pointers (include kg*8 lane offset)
    const f16* pw0h = W0h + (size_t)gc * K0 + kg * 8;
    const f16* pw0l = W0l + (size_t)gc * K0 + kg * 8;
    const f16* pw1h = W1h + (size_t)gc * K1 + kg * 8;
    const f16* pw1l = W1l + (size_t)gc * K1 + kg * 8;

    // A-frag element offsets into frag-layout h buffers (stride per k-slab = 512)
    const int rb0 = (row0 >> 4) + rowHalf * 2;
    const size_t aoff0 = ((size_t)(rb0 * 16) * 64 + lane) * 8;
    const size_t aoff1 = aoff0 + (size_t)16 * 64 * 8; // next 16-row block

    __shared__ float ldsG[2][4][64][17]; // [layer][gate][row][col], padded

    float c0[2] = {0.f, 0.f}, c1[2] = {0.f, 0.f};
    const int er = tid >> 3;        // epilogue row 0..63
    const int ej = (tid & 7) * 2;   // epilogue col pair
    const int ecol = colTile * 16 + ej;

    for (int p = 0; p <= NT; ++p) {
        const int pb = (p - 1) & 1; // h0(p-1) read buf; h1(p-1) write buf
        const int cb = p & 1;       // h0(p) write buf;  h1(p-2) read buf

        const f16* h0h = hb + (size_t)(0 + pb) * HBUF;
        const f16* h0l = hb + (size_t)(2 + pb) * HBUF;
        const f16* h1h = hb + (size_t)(4 + cb) * HBUF;
        const f16* h1l = hb + (size_t)(6 + cb) * HBUF;

        f32x4 a00 = {bi0, bi0, bi0, bi0}, a01 = a00; // L0 accum, frags 0/1
        f32x4 a10 = {bi1, bi1, bi1, bi1}, a11 = a10; // L1 accum

        f16x8 A0h[2], A0l[2], A1h[2], A1l[2];
        f16x8 B0h[2], B0l[2], B1h[2], B1l[2];

        // ---- slab 1: h0(p-1), K 0..511, feeds BOTH layers ----
#define LD_H0(s, b) do { const int _kb = (s) * 32; const size_t _ao = (size_t)(s) * 512;      \
        A0h[b] = cload(h0h + aoff0 + _ao); A0l[b] = cload(h0l + aoff0 + _ao);                 \
        A1h[b] = cload(h0h + aoff1 + _ao); A1l[b] = cload(h0l + aoff1 + _ao);                 \
        B0h[b] = *(const f16x8*)(pw0h + _kb); B0l[b] = *(const f16x8*)(pw0l + _kb);           \
        B1h[b] = *(const f16x8*)(pw1h + _kb); B1l[b] = *(const f16x8*)(pw1l + _kb); } while (0)

        LD_H0(0, 0);
#pragma unroll
        for (int s = 0; s < 16; ++s) {
            const int c_ = s & 1, n_ = c_ ^ 1;
            if (s < 15) LD_H0(s + 1, n_);
            a00 = MFMA16(A0h[c_], B0h[c_], a00); a00 = MFMA16(A0h[c_], B0l[c_], a00); a00 = MFMA16(A0l[c_], B0h[c_], a00);
            a01 = MFMA16(A1h[c_], B0h[c_], a01); a01 = MFMA16(A1h[c_], B0l[c_], a01); a01 = MFMA16(A1l[c_], B0h[c_], a01);
            a10 = MFMA16(A0h[c_], B1h[c_], a10); a10 = MFMA16(A0h[c_], B1l[c_], a10); a10 = MFMA16(A0l[c_], B1h[c_], a10);
            a11 = MFMA16(A1h[c_], B1h[c_], a11); a11 = MFMA16(A1h[c_], B1l[c_], a11); a11 = MFMA16(A1l[c_], B1h[c_], a11);
        }
#undef LD_H0

        // ---- slab 2: x_t (L0 only), weight K 512..639; plain loads, L2-cached ----
        if (p < NT) {
            const float* px0 = x + ((size_t)rA0 * NT + p) * NF + kg * 8;
            const float* px1 = x + ((size_t)rA1 * NT + p) * NF + kg * 8;
#pragma unroll
            for (int s = 0; s < 4; ++s) {
                const int fb = s * 32;
                f16x8 Xh0, Xl0, Xh1, Xl1;
                split8(px0 + fb, Xh0, Xl0);
                split8(px1 + fb, Xh1, Xl1);
                const int kb = NH + fb;
                f16x8 Wh = *(const f16x8*)(pw0h + kb);
                f16x8 Wl = *(const f16x8*)(pw0l + kb);
                a00 = MFMA16(Xh0, Wh, a00); a00 = MFMA16(Xh0, Wl, a00); a00 = MFMA16(Xl0, Wh, a00);
                a01 = MFMA16(Xh1, Wh, a01); a01 = MFMA16(Xh1, Wl, a01); a01 = MFMA16(Xl1, Wh, a01);
            }
        }

        // ---- slab 3: h1(p-2) (L1 only), weight K 512..1023 ----
#define LD_H1(s, b) do { const int _kb = NH + (s) * 32; const size_t _ao = (size_t)(s) * 512; \
        A0h[b] = cload(h1h + aoff0 + _ao); A0l[b] = cload(h1l + aoff0 + _ao);                 \
        A1h[b] = cload(h1h + aoff1 + _ao); A1l[b] = cload(h1l + aoff1 + _ao);                 \
        B1h[b] = *(const f16x8*)(pw1h + _kb); B1l[b] = *(const f16x8*)(pw1l + _kb); } while (0)

        LD_H1(0, 0);
#pragma unroll
        for (int s = 0; s < 16; ++s) {
            const int c_ = s & 1, n_ = c_ ^ 1;
            if (s < 15) LD_H1(s + 1, n_);
            a10 = MFMA16(A0h[c_], B1h[c_], a10); a10 = MFMA16(A0h[c_], B1l[c_], a10); a10 = MFMA16(A0l[c_], B1h[c_], a10);
            a11 = MFMA16(A1h[c_], B1h[c_], a11); a11 = MFMA16(A1h[c_], B1l[c_], a11); a11 = MFMA16(A1l[c_], B1h[c_], a11);
        }
#undef LD_H1

        // ---- dump gates to LDS (C/D layout: col=lane&15, row=(lane>>4)*4+reg) ----
#pragma unroll
        for (int rg = 0; rg < 4; ++rg) {
            const int r0w = rowHalf * 32 + kg * 4 + rg;
            ldsG[0][gate][r0w][lm] = a00[rg];
            ldsG[0][gate][r0w + 16][lm] = a01[rg];
            ldsG[1][gate][r0w][lm] = a10[rg];
            ldsG[1][gate][r0w + 16][lm] = a11[rg];
        }
        __syncthreads();

        // ---- fused cell updates (fp32) ----
        const int r = row0 + er;
        const size_t eoff = hidx(r, ecol); // 4B-aligned (ecol even)
        if (p < NT) {
            f16 hh[2], hl[2];
#pragma unroll
            for (int e = 0; e < 2; ++e) {
                const int jj = ej + e;
                const float gi = ldsG[0][0][er][jj];
                const float gf = ldsG[0][1][er][jj];
                const float gg = ldsG[0][2][er][jj];
                const float go = ldsG[0][3][er][jj];
                const float cn = sigf(gf) * c0[e] + sigf(gi) * tanhf(gg);
                c0[e] = cn;
                const float h = sigf(go) * tanhf(cn);
                hh[e] = (f16)h;
                hl[e] = (f16)(h - (float)hh[e]);
            }
            cstore2(hb + (size_t)(0 + cb) * HBUF + eoff, hh[0], hh[1]);
            cstore2(hb + (size_t)(2 + cb) * HBUF + eoff, hl[0], hl[1]);
        }
        if (p >= 1) {
            f16 hh[2], hl[2];
            float hv[2];
#pragma unroll
            for (int e = 0; e < 2; ++e) {
                const int jj = ej + e;
                const float gi = ldsG[1][0][er][jj];
                const float gf = ldsG[1][1][er][jj];
                const float gg = ldsG[1][2][er][jj];
                const float go = ldsG[1][3][er][jj];
                const float cn = sigf(gf) * c1[e] + sigf(gi) * tanhf(gg);
                c1[e] = cn;
                const float h = sigf(go) * tanhf(cn);
                hv[e] = h;
                hh[e] = (f16)h;
                hl[e] = (f16)(h - (float)hh[e]);
            }
            cstore2(hb + (size_t)(4 + pb) * HBUF + eoff, hh[0], hh[1]);
            cstore2(hb + (size_t)(6 + pb) * HBUF + eoff, hl[0], hl[1]);
            if (p == NT) {
                const size_t off = (size_t)r * NH + ecol;
                h1f[off] = hv[0];
                h1f[off + 1] = hv[1];
            }
        }

        // ---- fence-free grid barrier ----
        // syncthreads drains each thread's vmcnt (stores are sc0|sc1 write-through,
        // visible at the coherent point once retired); counter is agent-scope.
        if (p < NT) {
            __syncthreads();
            if (tid == 0) {
                __hip_atomic_fetch_add(ctr, 1u, __ATOMIC_RELAXED, __HIP_MEMORY_SCOPE_AGENT);
                const unsigned tgt = (unsigned)(p + 1) * NBLK;
                while (__hip_atomic_load(ctr, __ATOMIC_RELAXED, __HIP_MEMORY_SCOPE_AGENT) < tgt) {
                    __builtin_amdgcn_s_sleep(1);
                }
            }
            __syncthreads();
            asm volatile("" ::: "memory"); // compiler reorder barrier only
        }
    }
}

// ---------------- binarize + FC ----------------
__global__ __launch_bounds__(256) void fc_kernel(
    const float* __restrict__ h1f, const float* __restrict__ Wfc,
    const float* __restrict__ bfc, float* __restrict__ out)
{
    const int t = blockIdx.x * blockDim.x + threadIdx.x; // 0..16383
    const int b = t >> 5;
    const int o = t & 31;
    const float4* hr = (const float4*)(h1f + (size_t)b * NH);
    const float4* wr = (const float4*)(Wfc + (size_t)o * NH);
    float s = 0.f;
#pragma unroll 4
    for (int j = 0; j < NH / 4; ++j) {
        float4 h4 = hr[j];
        float4 w4 = wr[j];
        s += (h4.x > 0.f ? w4.x : 0.f) + (h4.y > 0.f ? w4.y : 0.f)
           + (h4.z > 0.f ? w4.z : 0.f) + (h4.w > 0.f ? w4.w : 0.f);
    }
    out[t] = s + bfc[o];
}

extern "C" void kernel_launch(void* const* d_in, const int* in_sizes, int n_in,
                              void* d_out, int out_size, void* d_ws, size_t ws_size,
                              hipStream_t stream) {
    const float* x    = (const float*)d_in[0];
    const float* Wih0 = (const float*)d_in[1];
    const float* Whh0 = (const float*)d_in[2];
    const float* bih0 = (const float*)d_in[3];
    const float* bhh0 = (const float*)d_in[4];
    const float* Wih1 = (const float*)d_in[5];
    const float* Whh1 = (const float*)d_in[6];
    const float* bih1 = (const float*)d_in[7];
    const float* bhh1 = (const float*)d_in[8];
    const float* Wfc  = (const float*)d_in[9];
    const float* bfc  = (const float*)d_in[10];
    float* out = (float*)d_out;
    (void)in_sizes; (void)n_in; (void)out_size; (void)ws_size;

    // workspace layout (~18.9 MB total)
    char* w = (char*)d_ws;
    unsigned* ctr = (unsigned*)w;                               // 256 B
    f16* hb = (f16*)(w + 256);                                  // 8 * 512 KB h split buffers
    char* after_hb = w + 256 + 8 * (size_t)HBUF * sizeof(f16);
    float* h1f = (float*)after_hb;                              // 1 MB
    float* bias0 = (float*)(after_hb + (size_t)NB * NH * 4);
    float* bias1 = bias0 + NGC;
    f16* W0h = (f16*)(bias1 + NGC);
    f16* W0l = W0h + (size_t)NGC * K0;
    f16* W1h = W0l + (size_t)NGC * K0;
    f16* W1l = W1h + (size_t)NGC * K1;

    // zero: counter + h state buffers (h(-1)=0); replayed each graph launch
    hipMemsetAsync(d_ws, 0, 256 + 8 * (size_t)HBUF * sizeof(f16), stream);

    prep_kernel<<<2048, 256, 0, stream>>>(Wih0, Whh0, bih0, bhh0, Wih1, Whh1, bih1, bhh1,
                                          W0h, W0l, W1h, W1l, bias0, bias1);

    lstm_kernel<<<NBLK, NTHR, 0, stream>>>(x, W0h, W0l, W1h, W1l, bias0, bias1, hb, ctr, h1f);

    fc_kernel<<<64, 256, 0, stream>>>(h1f, Wfc, bfc, out);
}

// Round 3
// 33883.649 us; speedup vs baseline: 2.6066x; 1.9683x over previous
//
#include <hip/hip_runtime.h>
#include <hip/hip_bf16.h>

// LSTM (2-layer, T=1024) + STE binarize + FC, MI355X.
// Round 3: inline-asm bypass loads (sc0 sc1) with counted vmcnt pipeline;
// wave remap (gate-pair x K-quarter) -> B read once/block, A dup 2x only;
// kq-partial gate reduction in LDS; layers sequential; fence-free barrier.

typedef _Float16 f16;
typedef __attribute__((ext_vector_type(8))) _Float16 f16x8;
typedef __attribute__((ext_vector_type(4))) float f32x4;

#define MFMA(a, b, c) __builtin_amdgcn_mfma_f32_16x16x32_f16((a), (b), (c), 0, 0, 0)
#define H8(v) __builtin_bit_cast(f16x8, v)

// bypass load (reads coherent point; does not allocate L1/L2)
#define GLB(dst, ptr) asm volatile("global_load_dwordx4 %0, %1, off sc0 sc1" : "=v"(dst) : "v"(ptr) : "memory")
// cached load (weights: L2-resident)
#define GLC(dst, ptr) asm volatile("global_load_dwordx4 %0, %1, off" : "=v"(dst) : "v"(ptr) : "memory")
#define VMWAIT(n) do { asm volatile("s_waitcnt vmcnt(" #n ")" ::: "memory"); __builtin_amdgcn_sched_barrier(0); } while (0)
#define DRAIN() do { asm volatile("s_waitcnt vmcnt(0)" ::: "memory"); __builtin_amdgcn_sched_barrier(0); } while (0)

#define NB 512
#define NT 1024
#define NF 128
#define NH 512
#define NGC 2048
#define K0 640      // NH + NF   (L0: [h0_prev | x_t])
#define K1 1024     // 2*NH      (L1: [h0_t | h1_prev])
#define HBUF 262144 // NB*NH
#define NBLK 256
#define NTHR 512

__device__ __forceinline__ float sigf(float v) { return 1.0f / (1.0f + expf(-v)); }

// coherent 4B (f16x2) store
__device__ __forceinline__ void cstore2(f16* p, f16 a, f16 b) {
    union { f16 h[2]; unsigned u; } x;
    x.h[0] = a; x.h[1] = b;
    __hip_atomic_store((unsigned*)p, x.u, __ATOMIC_RELAXED, __HIP_MEMORY_SCOPE_AGENT);
}

// fragment-native element index for h buffers:
// [rowblk r>>4][kblk c>>5][lane = ((c>>3)&3)*16 + (r&15)][elem c&7]
__device__ __forceinline__ size_t hidx(int r, int c) {
    return ((size_t)(((r >> 4) * 16 + (c >> 5)) * 64 + ((c >> 3) & 3) * 16 + (r & 15))) * 8 + (c & 7);
}

__device__ __forceinline__ void splitr(f32x4 u0, f32x4 u1, f16x8& hi, f16x8& lo) {
#pragma unroll
    for (int e = 0; e < 4; ++e) {
        float v = u0[e];
        f16 h = (f16)v;
        hi[e] = h;
        lo[e] = (f16)(v - (float)h);
    }
#pragma unroll
    for (int e = 0; e < 4; ++e) {
        float v = u1[e];
        f16 h = (f16)v;
        hi[4 + e] = h;
        lo[4 + e] = (f16)(v - (float)h);
    }
}

// ---------------- prep: split weights into packed hi/lo f16, sum biases ----------------
__global__ __launch_bounds__(256) void prep_kernel(
    const float* __restrict__ Wih0, const float* __restrict__ Whh0,
    const float* __restrict__ bih0, const float* __restrict__ bhh0,
    const float* __restrict__ Wih1, const float* __restrict__ Whh1,
    const float* __restrict__ bih1, const float* __restrict__ bhh1,
    f16* __restrict__ W0h, f16* __restrict__ W0l,
    f16* __restrict__ W1h, f16* __restrict__ W1l,
    float* __restrict__ bias0, float* __restrict__ bias1)
{
    const int stride = gridDim.x * blockDim.x;
    const int idx = blockIdx.x * blockDim.x + threadIdx.x;
    const int total0 = NGC * K0;
    for (int i = idx; i < total0; i += stride) {
        int gc = i / K0, k = i - gc * K0;
        float w = (k < NH) ? Whh0[gc * NH + k] : Wih0[gc * NF + (k - NH)];
        f16 h = (f16)w;
        W0h[i] = h;
        W0l[i] = (f16)(w - (float)h);
    }
    const int total1 = NGC * K1;
    for (int i = idx; i < total1; i += stride) {
        int gc = i / K1, k = i - gc * K1;
        float w = (k < NH) ? Wih1[gc * NH + k] : Whh1[gc * NH + (k - NH)];
        f16 h = (f16)w;
        W1h[i] = h;
        W1l[i] = (f16)(w - (float)h);
    }
    for (int i = idx; i < NGC; i += stride) {
        bias0[i] = bih0[i] + bhh0[i];
        bias1[i] = bih1[i] + bhh1[i];
    }
}

struct Stg { f32x4 Ah[4], Al[4], Bh[2], Bl[2]; };

// issue one K-step (32 k) of A frags: 4 rowblocks x (hi,lo) = 8 bypass loads
#define ISSUE_H(S, bh, bl, off) do { \
    GLB(S.Ah[0], (bh) + (off));         GLB(S.Al[0], (bl) + (off)); \
    GLB(S.Ah[1], (bh) + (off) + 16384); GLB(S.Al[1], (bl) + (off) + 16384); \
    GLB(S.Ah[2], (bh) + (off) + 32768); GLB(S.Al[2], (bl) + (off) + 32768); \
    GLB(S.Ah[3], (bh) + (off) + 49152); GLB(S.Al[3], (bl) + (off) + 49152); \
} while (0)
// issue one K-step of B frags: 2 gates x (hi,lo) = 4 cached loads
#define ISSUE_B(S, b0h, b0l, b1h, b1l, off) do { \
    GLC(S.Bh[0], (b0h) + (off)); GLC(S.Bl[0], (b0l) + (off)); \
    GLC(S.Bh[1], (b1h) + (off)); GLC(S.Bl[1], (b1l) + (off)); \
} while (0)
// 24 MFMAs: 4 frags x 2 gates x 3 split-products
#define STEP2(S) do { \
    _Pragma("unroll") for (int f = 0; f < 4; ++f) { \
        acc0[f] = MFMA(H8(S.Ah[f]), H8(S.Bh[0]), acc0[f]); \
        acc0[f] = MFMA(H8(S.Ah[f]), H8(S.Bl[0]), acc0[f]); \
        acc0[f] = MFMA(H8(S.Al[f]), H8(S.Bh[0]), acc0[f]); \
        acc1[f] = MFMA(H8(S.Ah[f]), H8(S.Bh[1]), acc1[f]); \
        acc1[f] = MFMA(H8(S.Ah[f]), H8(S.Bl[1]), acc1[f]); \
        acc1[f] = MFMA(H8(S.Al[f]), H8(S.Bh[1]), acc1[f]); \
    } } while (0)

#define ZACC() do { f32x4 _z = {0.f, 0.f, 0.f, 0.f}; \
    _Pragma("unroll") for (int f = 0; f < 4; ++f) { acc0[f] = _z; acc1[f] = _z; } } while (0)

#define DUMPG() do { \
    _Pragma("unroll") for (int f = 0; f < 4; ++f) \
    _Pragma("unroll") for (int rg = 0; rg < 4; ++rg) { \
        ldsG[kq][g0][f * 16 + kg * 4 + rg][lm] = acc0[f][rg]; \
        ldsG[kq][g0 + 1][f * 16 + kg * 4 + rg][lm] = acc1[f][rg]; \
    } } while (0)

// ---------------- main persistent LSTM kernel ----------------
__global__ __launch_bounds__(NTHR, 2) void lstm_kernel(
    const float* __restrict__ x,
    const f16* __restrict__ W0h, const f16* __restrict__ W0l,
    const f16* __restrict__ W1h, const f16* __restrict__ W1l,
    const float* __restrict__ bias0, const float* __restrict__ bias1,
    f16* hb, unsigned* ctr,
    float* __restrict__ h1f)
{
    const int tid = threadIdx.x;
    const int bid = blockIdx.x;
    const int lane = tid & 63;
    const int wave = tid >> 6;   // 0..7
    const int gp = wave & 1;     // gate pair 0:{i,f} 1:{g,o}
    const int kq = wave >> 1;    // K-quarter 0..3
    const int kg = lane >> 4;    // k-subgroup within 32
    const int lm = lane & 15;

    // XCD-aware tile map: colTile's weights stay on one XCD's L2
    const int xcd = bid & 7;
    const int sub = bid >> 3;
    const int colTile = xcd * 4 + (sub & 3); // 0..31 (16 h-cols)
    const int rowTile = sub >> 2;            // 0..7  (64 rows)
    const int row0 = rowTile * 64;
    const int rb0 = row0 >> 4;

    const int g0 = gp * 2;
    const int gc0 = g0 * NH + colTile * 16 + lm;
    const int gc1 = gc0 + NH;

    // weight pointers (bytes); per-stage offset = kstep*64
    const char* pb00h = (const char*)(W0h + (size_t)gc0 * K0 + kq * 128 + kg * 8);
    const char* pb00l = (const char*)(W0l + (size_t)gc0 * K0 + kq * 128 + kg * 8);
    const char* pb01h = (const char*)(W0h + (size_t)gc1 * K0 + kq * 128 + kg * 8);
    const char* pb01l = (const char*)(W0l + (size_t)gc1 * K0 + kq * 128 + kg * 8);
    const char* pb10h = (const char*)(W1h + (size_t)gc0 * K1 + kq * 256 + kg * 8);
    const char* pb10l = (const char*)(W1l + (size_t)gc0 * K1 + kq * 256 + kg * 8);
    const char* pb11h = (const char*)(W1h + (size_t)gc1 * K1 + kq * 256 + kg * 8);
    const char* pb11l = (const char*)(W1l + (size_t)gc1 * K1 + kq * 256 + kg * 8);

    // x-part W0 fragments are phase-invariant -> registers
    const f16x8 xB0h = *(const f16x8*)(W0h + (size_t)gc0 * K0 + NH + kq * 32 + kg * 8);
    const f16x8 xB0l = *(const f16x8*)(W0l + (size_t)gc0 * K0 + NH + kq * 32 + kg * 8);
    const f16x8 xB1h = *(const f16x8*)(W1h == nullptr ? nullptr : W0h + (size_t)gc1 * K0 + NH + kq * 32 + kg * 8);
    const f16x8 xB1l = *(const f16x8*)(W0l + (size_t)gc1 * K0 + NH + kq * 32 + kg * 8);

    // A-frag byte offsets into frag-layout h buffers
    const size_t abL0 = (((size_t)rb0 * 16 + kq * 4) * 64 + lane) * 16;
    const size_t abL1 = (((size_t)rb0 * 16 + (kq & 1) * 8) * 64 + lane) * 16;

    // epilogue mapping
    const int er = tid >> 3;
    const int ej = (tid & 7) * 2;
    const int ecol = colTile * 16 + ej;
    const size_t eoff = hidx(row0 + er, ecol);
    float bL0[4][2], bL1[4][2];
#pragma unroll
    for (int g = 0; g < 4; ++g)
#pragma unroll
        for (int e = 0; e < 2; ++e) {
            bL0[g][e] = bias0[g * NH + ecol + e];
            bL1[g][e] = bias1[g * NH + ecol + e];
        }

    __shared__ float ldsG[4][4][64][17]; // [kq][gate][row][col] partials

    float c0[2] = {0.f, 0.f}, c1[2] = {0.f, 0.f};
    f32x4 acc0[4], acc1[4];
    Stg sA, sB;

    for (int p = 0; p <= NT; ++p) {
        const int pb_ = (p - 1) & 1;
        const int cb_ = p & 1;
        const f16* h0h = hb + (size_t)(0 + pb_) * HBUF;
        const f16* h0l = hb + (size_t)(2 + pb_) * HBUF;
        const f16* h1h = hb + (size_t)(4 + cb_) * HBUF;
        const f16* h1l = hb + (size_t)(6 + cb_) * HBUF;

        // ================= L0 GEMM =================
        if (p < NT) {
            ZACC();
            // x part (compiler loads, L2-cached) — k range kq*32..+31
#pragma unroll
            for (int f = 0; f < 4; ++f) {
                const float* px = x + ((size_t)(row0 + f * 16 + lm) * NT + p) * NF + kq * 32 + kg * 8;
                f32x4 u0 = *(const f32x4*)px;
                f32x4 u1 = *(const f32x4*)(px + 4);
                f16x8 Ah, Al;
                splitr(u0, u1, Ah, Al);
                acc0[f] = MFMA(Ah, xB0h, acc0[f]); acc0[f] = MFMA(Ah, xB0l, acc0[f]); acc0[f] = MFMA(Al, xB0h, acc0[f]);
                acc1[f] = MFMA(Ah, xB1h, acc1[f]); acc1[f] = MFMA(Ah, xB1l, acc1[f]); acc1[f] = MFMA(Al, xB1h, acc1[f]);
            }
            DRAIN();
            // h0(p-1) slab: 4 K-steps, lookahead-1 counted pipeline
            const char* aH = (const char*)h0h + abL0;
            const char* aL = (const char*)h0l + abL0;
            ISSUE_H(sA, aH, aL, 0);    ISSUE_B(sA, pb00h, pb00l, pb01h, pb01l, 0);
            ISSUE_H(sB, aH, aL, 1024); ISSUE_B(sB, pb00h, pb00l, pb01h, pb01l, 64);
            VMWAIT(12); STEP2(sA);
            ISSUE_H(sA, aH, aL, 2048); ISSUE_B(sA, pb00h, pb00l, pb01h, pb01l, 128);
            VMWAIT(12); STEP2(sB);
            ISSUE_H(sB, aH, aL, 3072); ISSUE_B(sB, pb00h, pb00l, pb01h, pb01l, 192);
            VMWAIT(12); STEP2(sA);
            VMWAIT(0);  STEP2(sB);
            DUMPG();
        }
        __syncthreads();
        // ================= cell L0 =================
        if (p < NT) {
            float gs[4][2];
#pragma unroll
            for (int g = 0; g < 4; ++g)
#pragma unroll
                for (int e = 0; e < 2; ++e)
                    gs[g][e] = ldsG[0][g][er][ej + e] + ldsG[1][g][er][ej + e]
                             + ldsG[2][g][er][ej + e] + ldsG[3][g][er][ej + e] + bL0[g][e];
            f16 hh[2], hl[2];
#pragma unroll
            for (int e = 0; e < 2; ++e) {
                const float cn = sigf(gs[1][e]) * c0[e] + sigf(gs[0][e]) * tanhf(gs[2][e]);
                c0[e] = cn;
                const float h = sigf(gs[3][e]) * tanhf(cn);
                hh[e] = (f16)h;
                hl[e] = (f16)(h - (float)hh[e]);
            }
            cstore2(hb + (size_t)(0 + cb_) * HBUF + eoff, hh[0], hh[1]);
            cstore2(hb + (size_t)(2 + cb_) * HBUF + eoff, hl[0], hl[1]);
        }
        __syncthreads();
        // ================= L1 GEMM =================
        if (p >= 1) {
            ZACC();
            // kq 0,1 read h0(p-1) (k 0..511); kq 2,3 read h1(p-2) (k 512..1023)
            const char* aH = (kq < 2 ? (const char*)h0h : (const char*)h1h) + abL1;
            const char* aL = (kq < 2 ? (const char*)h0l : (const char*)h1l) + abL1;
            DRAIN();
            ISSUE_H(sA, aH, aL, 0);    ISSUE_B(sA, pb10h, pb10l, pb11h, pb11l, 0);
            ISSUE_H(sB, aH, aL, 1024); ISSUE_B(sB, pb10h, pb10l, pb11h, pb11l, 64);
            VMWAIT(12); STEP2(sA);
            ISSUE_H(sA, aH, aL, 2048); ISSUE_B(sA, pb10h, pb10l, pb11h, pb11l, 128);
            VMWAIT(12); STEP2(sB);
            ISSUE_H(sB, aH, aL, 3072); ISSUE_B(sB, pb10h, pb10l, pb11h, pb11l, 192);
            VMWAIT(12); STEP2(sA);
            ISSUE_H(sA, aH, aL, 4096); ISSUE_B(sA, pb10h, pb10l, pb11h, pb11l, 256);
            VMWAIT(12); STEP2(sB);
            ISSUE_H(sB, aH, aL, 5120); ISSUE_B(sB, pb10h, pb10l, pb11h, pb11l, 320);
            VMWAIT(12); STEP2(sA);
            ISSUE_H(sA, aH, aL, 6144); ISSUE_B(sA, pb10h, pb10l, pb11h, pb11l, 384);
            VMWAIT(12); STEP2(sB);
            ISSUE_H(sB, aH, aL, 7168); ISSUE_B(sB, pb10h, pb10l, pb11h, pb11l, 448);
            VMWAIT(12); STEP2(sA);
            VMWAIT(0);  STEP2(sB);
            DUMPG();
        }
        __syncthreads();
        // ================= cell L1 =================
        if (p >= 1) {
            float gs[4][2];
#pragma unroll
            for (int g = 0; g < 4; ++g)
#pragma unroll
                for (int e = 0; e < 2; ++e)
                    gs[g][e] = ldsG[0][g][er][ej + e] + ldsG[1][g][er][ej + e]
                             + ldsG[2][g][er][ej + e] + ldsG[3][g][er][ej + e] + bL1[g][e];
            f16 hh[2], hl[2];
            float hv[2];
#pragma unroll
            for (int e = 0; e < 2; ++e) {
                const float cn = sigf(gs[1][e]) * c1[e] + sigf(gs[0][e]) * tanhf(gs[2][e]);
                c1[e] = cn;
                const float h = sigf(gs[3][e]) * tanhf(cn);
                hv[e] = h;
                hh[e] = (f16)h;
                hl[e] = (f16)(h - (float)hh[e]);
            }
            cstore2(hb + (size_t)(4 + pb_) * HBUF + eoff, hh[0], hh[1]);
            cstore2(hb + (size_t)(6 + pb_) * HBUF + eoff, hl[0], hl[1]);
            if (p == NT) {
                const size_t off = (size_t)(row0 + er) * NH + ecol;
                h1f[off] = hv[0];
                h1f[off + 1] = hv[1];
            }
        }
        // ================= grid barrier =================
        if (p < NT) {
            __syncthreads(); // drains vmcnt (stores visible at coherent point)
            if (tid == 0) {
                __hip_atomic_fetch_add(ctr, 1u, __ATOMIC_RELAXED, __HIP_MEMORY_SCOPE_AGENT);
                const unsigned tgt = (unsigned)(p + 1) * NBLK;
                while (__hip_atomic_load(ctr, __ATOMIC_RELAXED, __HIP_MEMORY_SCOPE_AGENT) < tgt) {
                    __builtin_amdgcn_s_sleep(1);
                }
            }
            __syncthreads();
            asm volatile("" ::: "memory");
        }
    }
}

// ---------------- binarize + FC ----------------
__global__ __launch_bounds__(256) void fc_kernel(
    const float* __restrict__ h1f, const float* __restrict__ Wfc,
    const float* __restrict__ bfc, float* __restrict__ out)
{
    const int t = blockIdx.x * blockDim.x + threadIdx.x; // 0..16383
    const int b = t >> 5;
    const int o = t & 31;
    const float4* hr = (const float4*)(h1f + (size_t)b * NH);
    const float4* wr = (const float4*)(Wfc + (size_t)o * NH);
    float s = 0.f;
#pragma unroll 4
    for (int j = 0; j < NH / 4; ++j) {
        float4 h4 = hr[j];
        float4 w4 = wr[j];
        s += (h4.x > 0.f ? w4.x : 0.f) + (h4.y > 0.f ? w4.y : 0.f)
           + (h4.z > 0.f ? w4.z : 0.f) + (h4.w > 0.f ? w4.w : 0.f);
    }
    out[t] = s + bfc[o];
}

extern "C" void kernel_launch(void* const* d_in, const int* in_sizes, int n_in,
                              void* d_out, int out_size, void* d_ws, size_t ws_size,
                              hipStream_t stream) {
    const float* x    = (const float*)d_in[0];
    const float* Wih0 = (const float*)d_in[1];
    const float* Whh0 = (const float*)d_in[2];
    const float* bih0 = (const float*)d_in[3];
    const float* bhh0 = (const float*)d_in[4];
    const float* Wih1 = (const float*)d_in[5];
    const float* Whh1 = (const float*)d_in[6];
    const float* bih1 = (const float*)d_in[7];
    const float* bhh1 = (const float*)d_in[8];
    const float* Wfc  = (const float*)d_in[9];
    const float* bfc  = (const float*)d_in[10];
    float* out = (float*)d_out;
    (void)in_sizes; (void)n_in; (void)out_size; (void)ws_size;

    char* w = (char*)d_ws;
    unsigned* ctr = (unsigned*)w;                               // 256 B
    f16* hb = (f16*)(w + 256);                                  // 8 * 512 KB h split buffers
    char* after_hb = w + 256 + 8 * (size_t)HBUF * sizeof(f16);
    float* h1f = (float*)after_hb;                              // 1 MB
    float* bias0 = (float*)(after_hb + (size_t)NB * NH * 4);
    float* bias1 = bias0 + NGC;
    f16* W0h = (f16*)(bias1 + NGC);
    f16* W0l = W0h + (size_t)NGC * K0;
    f16* W1h = W0l + (size_t)NGC * K0;
    f16* W1l = W1h + (size_t)NGC * K1;

    hipMemsetAsync(d_ws, 0, 256 + 8 * (size_t)HBUF * sizeof(f16), stream);

    prep_kernel<<<2048, 256, 0, stream>>>(Wih0, Whh0, bih0, bhh0, Wih1, Whh1, bih1, bhh1,
                                          W0h, W0l, W1h, W1l, bias0, bias1);

    lstm_kernel<<<NBLK, NTHR, 0, stream>>>(x, W0h, W0l, W1h, W1l, bias0, bias1, hb, ctr, h1f);

    fc_kernel<<<64, 256, 0, stream>>>(h1f, Wfc, bfc, out);
}